// Round 1
// baseline (359.149 us; speedup 1.0000x reference)
//
#include <hip/hip_runtime.h>
#include <math.h>

#define SRC_LEN 2048
#define BATCH   32
#define EHID    1024   // 2*enc_hid_dim (inner dim of enc_outputs)
#define DHID    1024   // dec_hid_dim

// Kernel 1: dec_e[b] = dot(dec_hidden[b,:], W[0,0:DHID]) + bias
// 32 blocks x 256 threads; each thread handles one float4 (256*4 = 1024).
__global__ void dec_dot_kernel(const float* __restrict__ dec_hidden,
                               const float* __restrict__ W,
                               const float* __restrict__ bias,
                               float* __restrict__ dec_e) {
    const int b = blockIdx.x;
    const int t = threadIdx.x;
    const float4* dh = (const float4*)(dec_hidden + (size_t)b * DHID);
    const float4* w  = (const float4*)W;
    float4 a  = dh[t];
    float4 ww = w[t];
    float acc = a.x * ww.x + a.y * ww.y + a.z * ww.z + a.w * ww.w;
    #pragma unroll
    for (int off = 32; off > 0; off >>= 1)
        acc += __shfl_down(acc, off, 64);
    __shared__ float smem[4];
    const int wid  = t >> 6;
    const int lane = t & 63;
    if (lane == 0) smem[wid] = acc;
    __syncthreads();
    if (t == 0)
        dec_e[b] = smem[0] + smem[1] + smem[2] + smem[3] + bias[0];
}

// Kernel 2: one wave per (s,b) pair. p[b,s] = exp(tanh(dec_e[b] + enc[s,b,:].w_enc))
// Pair index == linear order of enc_outputs rows -> block reads contiguous 16 KB.
__global__ void score_kernel(const float* __restrict__ enc,    // [s][b][e]
                             const float* __restrict__ W,      // w_enc at W+DHID
                             const float* __restrict__ dec_e,  // [BATCH]
                             float* __restrict__ out) {        // [b][s]
    const int wid  = threadIdx.x >> 6;          // 4 waves/block
    const int lane = threadIdx.x & 63;
    const int pair = blockIdx.x * 4 + wid;      // pair = s*BATCH + b
    const int s    = pair >> 5;                 // / BATCH
    const int b    = pair & 31;                 // % BATCH

    const float4* row = (const float4*)(enc + (size_t)pair * EHID);
    const float4* w   = (const float4*)(W + DHID);

    float acc = 0.0f;
    #pragma unroll
    for (int i = 0; i < 4; ++i) {
        float4 a  = row[lane + 64 * i];   // 64 lanes x 16 B = 1 KB coalesced
        float4 ww = w[lane + 64 * i];     // shared across waves -> L1/L2 hit
        acc = fmaf(a.x, ww.x, acc);
        acc = fmaf(a.y, ww.y, acc);
        acc = fmaf(a.z, ww.z, acc);
        acc = fmaf(a.w, ww.w, acc);
    }
    #pragma unroll
    for (int off = 32; off > 0; off >>= 1)
        acc += __shfl_down(acc, off, 64);

    if (lane == 0) {
        float e = dec_e[b] + acc;
        // tanh in [-1,1] -> exp in [0.37, 2.72]: safe without max-subtraction
        out[(size_t)b * SRC_LEN + s] = expf(tanhf(e));
    }
}

// Kernel 3: per-row normalize. 32 blocks (one per batch) x 256 threads.
__global__ void softmax_norm_kernel(float* __restrict__ out) {
    const int b = blockIdx.x;
    const int t = threadIdx.x;
    float4* row = (float4*)(out + (size_t)b * SRC_LEN);  // 512 float4
    float4 v0 = row[t];
    float4 v1 = row[t + 256];
    float acc = v0.x + v0.y + v0.z + v0.w + v1.x + v1.y + v1.z + v1.w;
    #pragma unroll
    for (int off = 32; off > 0; off >>= 1)
        acc += __shfl_down(acc, off, 64);
    __shared__ float smem[4];
    const int wid  = t >> 6;
    const int lane = t & 63;
    if (lane == 0) smem[wid] = acc;
    __syncthreads();
    const float inv = 1.0f / (smem[0] + smem[1] + smem[2] + smem[3]);
    v0.x *= inv; v0.y *= inv; v0.z *= inv; v0.w *= inv;
    v1.x *= inv; v1.y *= inv; v1.z *= inv; v1.w *= inv;
    row[t]       = v0;
    row[t + 256] = v1;
}

extern "C" void kernel_launch(void* const* d_in, const int* in_sizes, int n_in,
                              void* d_out, int out_size, void* d_ws, size_t ws_size,
                              hipStream_t stream) {
    const float* dec_hidden = (const float*)d_in[0];  // (32, 1024)
    const float* enc        = (const float*)d_in[1];  // (2048, 32, 1024)
    const float* W          = (const float*)d_in[2];  // (1, 2048)
    const float* bias       = (const float*)d_in[3];  // (1,)
    float* out   = (float*)d_out;                     // (32, 2048)
    float* dec_e = (float*)d_ws;                      // 32 floats scratch

    dec_dot_kernel<<<BATCH, 256, 0, stream>>>(dec_hidden, W, bias, dec_e);
    score_kernel<<<(SRC_LEN * BATCH) / 4, 256, 0, stream>>>(enc, W, dec_e, out);
    softmax_norm_kernel<<<BATCH, 256, 0, stream>>>(out);
}